// Round 2
// baseline (320.079 us; speedup 1.0000x reference)
//
#include <hip/hip_runtime.h>

// PatchEmbedder: out[b,p,:] = patch_mask[b,p] ? sum_n sum_l mask_n[b,p,l]*emb_n[ids_n[b,p,l],:] : 0
// B=8, P=1024, D=512, L=(8,7,6). One wave per patch; lane holds 8 floats (2x float4).
//
// R1 lesson: per-id `if (mask)` branches serialized the gathers (waitcnt on mask,
// branch, then load) -> ~0.33 TB/s, latency-bound. R2: fully predicated — all row
// loads issue unconditionally (masked ids redirect to row 0, L2-hot), weight 0/1
// applied in the FMA. Loads batched into register arrays so 2L stay in flight.

#define D_DIM 512
#define NPATCH 8192  // B*P

template <int L>
__device__ __forceinline__ void gather_sum(const int* __restrict__ ids,
                                           const int* __restrict__ mask,
                                           const float* __restrict__ emb,
                                           int lane, float4& acc0, float4& acc1) {
    size_t off[L];
    float  w[L];
#pragma unroll
    for (int l = 0; l < L; ++l) {
        const int m = mask[l];
        off[l] = m ? (size_t)ids[l] * D_DIM : (size_t)0;  // masked -> row 0 (cache-hot dummy)
        w[l]   = m ? 1.0f : 0.0f;
    }
    float4 r0[L], r1[L];
#pragma unroll
    for (int l = 0; l < L; ++l) {   // issue all 2L loads back-to-back
        const float4* row = (const float4*)(emb + off[l]);
        r0[l] = row[lane];
        r1[l] = row[64 + lane];
    }
#pragma unroll
    for (int l = 0; l < L; ++l) {
        acc0.x += w[l] * r0[l].x; acc0.y += w[l] * r0[l].y;
        acc0.z += w[l] * r0[l].z; acc0.w += w[l] * r0[l].w;
        acc1.x += w[l] * r1[l].x; acc1.y += w[l] * r1[l].y;
        acc1.z += w[l] * r1[l].z; acc1.w += w[l] * r1[l].w;
    }
}

__global__ __launch_bounds__(256) void patch_embed_kernel(
    const int* __restrict__ ids1, const int* __restrict__ m1, const float* __restrict__ e1,
    const int* __restrict__ ids2, const int* __restrict__ m2, const float* __restrict__ e2,
    const int* __restrict__ ids3, const int* __restrict__ m3, const float* __restrict__ e3,
    const int* __restrict__ pmask, float* __restrict__ out) {
    const int wave  = threadIdx.x >> 6;
    const int lane  = threadIdx.x & 63;
    const int patch = (blockIdx.x << 2) | wave;   // 4 waves/block, one patch each

    float4 acc0 = make_float4(0.f, 0.f, 0.f, 0.f);
    float4 acc1 = make_float4(0.f, 0.f, 0.f, 0.f);

    if (pmask[patch]) {   // wave-uniform; skips all gather traffic for dead patches
        gather_sum<8>(ids1 + patch * 8, m1 + patch * 8, e1, lane, acc0, acc1);
        gather_sum<7>(ids2 + patch * 7, m2 + patch * 7, e2, lane, acc0, acc1);
        gather_sum<6>(ids3 + patch * 6, m3 + patch * 6, e3, lane, acc0, acc1);
    }

    float4* outv = (float4*)(out + (size_t)patch * D_DIM);
    outv[lane]      = acc0;
    outv[64 + lane] = acc1;
}

extern "C" void kernel_launch(void* const* d_in, const int* in_sizes, int n_in,
                              void* d_out, int out_size, void* d_ws, size_t ws_size,
                              hipStream_t stream) {
    // setup_inputs() dict order:
    // 0 ids_1[8,1024,8] i64->int, 1 mask_1[8,1024,8] bool->int, 2 emb_1[65536,512] f32,
    // 3 ids_2[8,1024,7],          4 mask_2[8,1024,7],           5 emb_2[65536,512],
    // 6 ids_3[8,1024,6],          7 mask_3[8,1024,6],           8 emb_3[65536,512],
    // 9 patch_mask[8,1024] bool->int
    const int*   ids1  = (const int*)d_in[0];
    const int*   m1    = (const int*)d_in[1];
    const float* e1    = (const float*)d_in[2];
    const int*   ids2  = (const int*)d_in[3];
    const int*   m2    = (const int*)d_in[4];
    const float* e2    = (const float*)d_in[5];
    const int*   ids3  = (const int*)d_in[6];
    const int*   m3    = (const int*)d_in[7];
    const float* e3    = (const float*)d_in[8];
    const int*   pmask = (const int*)d_in[9];
    float* out = (float*)d_out;

    dim3 grid(NPATCH / 4);   // 2048 blocks x 4 waves = 8192 patches
    dim3 block(256);
    patch_embed_kernel<<<grid, block, 0, stream>>>(ids1, m1, e1, ids2, m2, e2,
                                                   ids3, m3, e3, pmask, out);
}

// Round 3
// 310.477 us; speedup vs baseline: 1.0309x; 1.0309x over previous
//
#include <hip/hip_runtime.h>

// PatchEmbedder: out[b,p,:] = patch_mask[b,p] ? sum_n sum_l mask_n[b,p,l]*emb_n[ids_n[b,p,l],:] : 0
// B=8, P=1024, D=512, L=(8,7,6). R3: two waves per patch (each wave owns a
// 256-float half; 1 float4/lane). All 21 ids/masks scalarized via
// readfirstlane (wave-uniform) -> row bases in SGPRs; all 21 row loads issued
// as one flat batch before any accumulate, masked ids redirected to row 0
// (L2-hot) with weight 0. Evidence R1/R2: kernel < 77 us (absent from rocprof
// top-5); total dur dominated by harness poison/restore passes.

#define D_DIM 512
#define NPATCH 8192   // B*P
#define NGATHER 21    // 8+7+6

__global__ __launch_bounds__(256) void patch_embed_kernel(
    const int* __restrict__ ids1, const int* __restrict__ m1, const float* __restrict__ e1,
    const int* __restrict__ ids2, const int* __restrict__ m2, const float* __restrict__ e2,
    const int* __restrict__ ids3, const int* __restrict__ m3, const float* __restrict__ e3,
    const int* __restrict__ pmask, float* __restrict__ out) {
    const int tid   = threadIdx.x;
    const int wave  = tid >> 6;
    const int lane  = tid & 63;
    const int gwave = (blockIdx.x << 2) | wave;  // 0..16383
    const int patch = gwave >> 1;                // 2 waves per patch
    const int fidx  = ((gwave & 1) << 6) | lane; // float4 index in row, 0..127

    float4 acc = make_float4(0.f, 0.f, 0.f, 0.f);

    if (pmask[patch]) {   // wave-uniform
        const float* base[NGATHER];
        float        w[NGATHER];

        const int* idp[3]  = {ids1 + patch * 8, ids2 + patch * 7, ids3 + patch * 6};
        const int* mp[3]   = {m1 + patch * 8,   m2 + patch * 7,   m3 + patch * 6};
        const float* ep[3] = {e1, e2, e3};
        const int  Ln[3]   = {8, 7, 6};

        int k = 0;
#pragma unroll
        for (int n = 0; n < 3; ++n) {
#pragma unroll
            for (int l = 0; l < 8; ++l) {
                if (l < Ln[n]) {
                    const int id = __builtin_amdgcn_readfirstlane(idp[n][l]);
                    const int m  = __builtin_amdgcn_readfirstlane(mp[n][l]);
                    base[k] = ep[n] + (size_t)(m ? id : 0) * D_DIM;  // masked -> row 0 (cache-hot)
                    w[k]    = m ? 1.0f : 0.0f;
                    ++k;
                }
            }
        }

        float4 r[NGATHER];
#pragma unroll
        for (int i = 0; i < NGATHER; ++i)   // all 21 loads in flight before first use
            r[i] = ((const float4*)base[i])[fidx];

#pragma unroll
        for (int i = 0; i < NGATHER; ++i) {
            acc.x += w[i] * r[i].x;
            acc.y += w[i] * r[i].y;
            acc.z += w[i] * r[i].z;
            acc.w += w[i] * r[i].w;
        }
    }

    ((float4*)(out + (size_t)patch * D_DIM))[fidx] = acc;
}

extern "C" void kernel_launch(void* const* d_in, const int* in_sizes, int n_in,
                              void* d_out, int out_size, void* d_ws, size_t ws_size,
                              hipStream_t stream) {
    // setup_inputs() dict order:
    // 0 ids_1[8,1024,8] i64->int, 1 mask_1[8,1024,8] bool->int, 2 emb_1[65536,512] f32,
    // 3 ids_2[8,1024,7],          4 mask_2[8,1024,7],           5 emb_2[65536,512],
    // 6 ids_3[8,1024,6],          7 mask_3[8,1024,6],           8 emb_3[65536,512],
    // 9 patch_mask[8,1024] bool->int
    const int*   ids1  = (const int*)d_in[0];
    const int*   m1    = (const int*)d_in[1];
    const float* e1    = (const float*)d_in[2];
    const int*   ids2  = (const int*)d_in[3];
    const int*   m2    = (const int*)d_in[4];
    const float* e2    = (const float*)d_in[5];
    const int*   ids3  = (const int*)d_in[6];
    const int*   m3    = (const int*)d_in[7];
    const float* e3    = (const float*)d_in[8];
    const int*   pmask = (const int*)d_in[9];
    float* out = (float*)d_out;

    dim3 grid(NPATCH * 2 / 4);  // 4096 blocks x 4 waves = 16384 waves = 2/patch
    dim3 block(256);
    patch_embed_kernel<<<grid, block, 0, stream>>>(ids1, m1, e1, ids2, m2, e2,
                                                   ids3, m3, e3, pmask, out);
}